// Round 4
// baseline (1641.208 us; speedup 1.0000x reference)
//
#include <hip/hip_runtime.h>
#include <math.h>

#define H_    16
#define S_    2048
#define MTOK  8192   // B*S

typedef __bf16 bf16_t;
typedef bf16_t bf16x4 __attribute__((ext_vector_type(4)));
typedef bf16_t bf16x8 __attribute__((ext_vector_type(8)));
typedef float  f32x4  __attribute__((ext_vector_type(4)));

__device__ inline f32x4 mfma16(bf16x8 a, bf16x8 b, f32x4 c) {
    return __builtin_amdgcn_mfma_f32_16x16x32_bf16(a, b, c, 0, 0, 0);
}

#define GLOAD_LDS(gp, lp)                                                      \
    __builtin_amdgcn_global_load_lds(                                          \
        (const __attribute__((address_space(1))) void*)(gp),                   \
        (__attribute__((address_space(3))) void*)(lp), 16, 0, 0)

// ---------------------------------------------------------------------------
__global__ __launch_bounds__(256) void cast_bf16(const float* __restrict__ in,
                                                 bf16_t* __restrict__ out, int n) {
    const int i = (blockIdx.x * 256 + threadIdx.x) * 4;
    if (i < n) {
        float4 v = *(const float4*)&in[i];
        bf16x4 o = {(bf16_t)v.x, (bf16_t)v.y, (bf16_t)v.z, (bf16_t)v.w};
        *(bf16x4*)&out[i] = o;
    }
}

// W (KxN fp32) -> Wt (NxK bf16)
__global__ __launch_bounds__(256) void transpose_cast(const float* __restrict__ W,
                                                      bf16_t* __restrict__ Wt,
                                                      int K, int N) {
    __shared__ float t[32][33];
    const int x = threadIdx.x & 31, y = threadIdx.x >> 5;
    const int k0 = blockIdx.y * 32, n0 = blockIdx.x * 32;
#pragma unroll
    for (int j = 0; j < 4; ++j)
        t[y + j * 8][x] = W[(size_t)(k0 + y + j * 8) * N + n0 + x];
    __syncthreads();
#pragma unroll
    for (int j = 0; j < 4; ++j)
        Wt[(size_t)(n0 + y + j * 8) * K + k0 + x] = (bf16_t)t[x][y + j * 8];
}

// ---------------------------------------------------------------------------
// MFMA GEMM, 128x128 tile, BK=32, m97-style global_load_lds staging.
// EP 5: fp32 row-major (out-proj)
// EP 6: down-proj fused: n<512 -> ckv bf16; n<1024 -> cq; n<1088 -> k_r RoPE
//       broadcast into Kb[..,64:]; n>=1088 dead (garbage B rows, not stored)
// EP 7: up1 (A=ckv): n<1024 -> Kb[..,:64] scatter; else -> Vt (B*H,64,S)
// EP 8: up2 (A=cq):  n<1024 -> Qb[..,:64] scatter; else RoPE -> Qb[..,64:]
// ---------------------------------------------------------------------------
template <int EP>
__global__ __launch_bounds__(256) void mgemm(const bf16_t* __restrict__ A,
                                             const bf16_t* __restrict__ Bt,
                                             const float* __restrict__ bias,
                                             const float* __restrict__ bias2,
                                             const float* __restrict__ bias3,
                                             void* __restrict__ Cv,
                                             void* __restrict__ Cv2,
                                             void* __restrict__ Cv3,
                                             int M, int N, int K) {
    __shared__ bf16_t As[4096];
    __shared__ bf16_t Bs[4096];

    const int tid = threadIdx.x;
    const int lane = tid & 63, wave = tid >> 6;
    const int n16 = lane & 15, quad = lane >> 4;
    const int wm = wave & 1, wn = wave >> 1;
    const int m0 = blockIdx.y * 128, n0 = blockIdx.x * 128;

    const int crow = tid >> 2, ccol = (tid & 3) * 8;
    const bf16_t* Ag0 = A + (size_t)(m0 + crow) * K + ccol;
    const bf16_t* Ag1 = A + (size_t)(m0 + crow + 64) * K + ccol;
    const bf16_t* Bg0 = Bt + (size_t)(n0 + crow) * K + ccol;
    const bf16_t* Bg1 = Bt + (size_t)(n0 + crow + 64) * K + ccol;
    bf16_t* Al0 = As + wave * 512;
    bf16_t* Al1 = As + 2048 + wave * 512;
    bf16_t* Bl0 = Bs + wave * 512;
    bf16_t* Bl1 = Bs + 2048 + wave * 512;

    f32x4 acc[4][4] = {};

    for (int k0 = 0; k0 < K; k0 += 32) {
        GLOAD_LDS(Ag0 + k0, Al0);
        GLOAD_LDS(Ag1 + k0, Al1);
        GLOAD_LDS(Bg0 + k0, Bl0);
        GLOAD_LDS(Bg1 + k0, Bl1);
        __syncthreads();
        bf16x8 af[4], bfr[4];
#pragma unroll
        for (int mt = 0; mt < 4; ++mt)
            af[mt] = *(const bf16x8*)&As[(wm * 64 + mt * 16 + n16) * 32 + quad * 8];
#pragma unroll
        for (int nt = 0; nt < 4; ++nt)
            bfr[nt] = *(const bf16x8*)&Bs[(wn * 64 + nt * 16 + n16) * 32 + quad * 8];
#pragma unroll
        for (int mt = 0; mt < 4; ++mt)
#pragma unroll
            for (int nt = 0; nt < 4; ++nt)
                acc[mt][nt] = mfma16(af[mt], bfr[nt], acc[mt][nt]);
        __syncthreads();
    }

    const int mbase = m0 + wm * 64;
    const int nbase = n0 + wn * 64;
#pragma unroll
    for (int nt = 0; nt < 4; ++nt) {
        const int n = nbase + nt * 16 + n16;
        if constexpr (EP == 5) {
            float* C = (float*)Cv;
            const float bv = bias[n];
#pragma unroll
            for (int mt = 0; mt < 4; ++mt)
#pragma unroll
                for (int r = 0; r < 4; ++r) {
                    const int m = mbase + mt * 16 + quad * 4 + r;
                    C[(size_t)m * N + n] = acc[mt][nt][r] + bv;
                }
        } else if constexpr (EP == 6) {
            if (n < 512) {
                bf16_t* C = (bf16_t*)Cv;  // ckv
                const float bv = bias[n];
#pragma unroll
                for (int mt = 0; mt < 4; ++mt)
#pragma unroll
                    for (int r = 0; r < 4; ++r) {
                        const int m = mbase + mt * 16 + quad * 4 + r;
                        C[(size_t)m * 512 + n] = (bf16_t)(acc[mt][nt][r] + bv);
                    }
            } else if (n < 1024) {
                bf16_t* C = (bf16_t*)Cv2;  // cq
                const float bv = bias2[n - 512];
#pragma unroll
                for (int mt = 0; mt < 4; ++mt)
#pragma unroll
                    for (int r = 0; r < 4; ++r) {
                        const int m = mbase + mt * 16 + quad * 4 + r;
                        C[(size_t)m * 512 + (n - 512)] = (bf16_t)(acc[mt][nt][r] + bv);
                    }
            } else if (n < 1088) {
                bf16_t* C = (bf16_t*)Cv3;  // Kb, RoPE + broadcast over heads
                const int d = n - 1024;
                const float bv = bias3[d];
                const float fr = exp2f(-(float)(d >> 1) * 0.4152410118609203f);
                const float sgn = (d & 1) ? 1.0f : -1.0f;
#pragma unroll
                for (int mt = 0; mt < 4; ++mt)
#pragma unroll
                    for (int r = 0; r < 4; ++r) {
                        const int m = mbase + mt * 16 + quad * 4 + r;
                        const int b = m >> 11, s = m & 2047;
                        const float v = acc[mt][nt][r] + bv;
                        const float vp = __shfl_xor(v, 1);
                        float sn, cs;
                        sincosf((float)s * fr, &sn, &cs);
                        const bf16_t o = (bf16_t)(v * cs + sgn * vp * sn);
                        for (int h = 0; h < H_; ++h)
                            C[((size_t)(b * H_ + h) * S_ + s) * 128 + 64 + d] = o;
                    }
            }
        } else if constexpr (EP == 7) {
            if (n < 1024) {
                bf16_t* C = (bf16_t*)Cv;  // Kb cols 0..63
                const int h = n >> 6, c = n & 63;
                const float bv = bias[n];
#pragma unroll
                for (int mt = 0; mt < 4; ++mt)
#pragma unroll
                    for (int r = 0; r < 4; ++r) {
                        const int m = mbase + mt * 16 + quad * 4 + r;
                        const int b = m >> 11, s = m & 2047;
                        C[((size_t)(b * H_ + h) * S_ + s) * 128 + c] =
                            (bf16_t)(acc[mt][nt][r] + bv);
                    }
            } else {
                bf16_t* C = (bf16_t*)Cv2;  // Vt (B*H,64,S)
                const int nn = n - 1024;
                const int h = nn >> 6, vd = nn & 63;
                const float bv = bias2[nn];
#pragma unroll
                for (int mt = 0; mt < 4; ++mt) {
                    const int s0 = mbase + mt * 16 + quad * 4;
                    const int b = s0 >> 11, s = s0 & 2047;
                    bf16x4 o = {(bf16_t)(acc[mt][nt][0] + bv), (bf16_t)(acc[mt][nt][1] + bv),
                                (bf16_t)(acc[mt][nt][2] + bv), (bf16_t)(acc[mt][nt][3] + bv)};
                    *(bf16x4*)&C[((size_t)(b * H_ + h) * 64 + vd) * S_ + s] = o;
                }
            }
        } else {  // EP == 8
            if (n < 1024) {
                bf16_t* C = (bf16_t*)Cv;  // Qb cols 0..63
                const int h = n >> 6, c = n & 63;
                const float bv = bias[n];
#pragma unroll
                for (int mt = 0; mt < 4; ++mt)
#pragma unroll
                    for (int r = 0; r < 4; ++r) {
                        const int m = mbase + mt * 16 + quad * 4 + r;
                        const int b = m >> 11, s = m & 2047;
                        C[((size_t)(b * H_ + h) * S_ + s) * 128 + c] =
                            (bf16_t)(acc[mt][nt][r] + bv);
                    }
            } else {
                bf16_t* C = (bf16_t*)Cv;  // Qb cols 64..127 with RoPE
                const int nn = n - 1024;
                const int h = nn >> 6, d = nn & 63;
                const float bv = bias2[nn];
                const float fr = exp2f(-(float)(d >> 1) * 0.4152410118609203f);
                const float sgn = (d & 1) ? 1.0f : -1.0f;
#pragma unroll
                for (int mt = 0; mt < 4; ++mt)
#pragma unroll
                    for (int r = 0; r < 4; ++r) {
                        const int m = mbase + mt * 16 + quad * 4 + r;
                        const int b = m >> 11, s = m & 2047;
                        const float v = acc[mt][nt][r] + bv;
                        const float vp = __shfl_xor(v, 1);
                        float sn, cs;
                        sincosf((float)s * fr, &sn, &cs);
                        C[((size_t)(b * H_ + h) * S_ + s) * 128 + 64 + d] =
                            (bf16_t)(v * cs + sgn * vp * sn);
                    }
            }
        }
    }
}

// ---------------------------------------------------------------------------
// Folded flash attention: block j handles q-tiles j and 31-j -> uniform 33
// K-tile iterations per block. K-tile = 64 keys.
// ---------------------------------------------------------------------------
__device__ __forceinline__ void flash_pass(
    const bf16_t* __restrict__ Qg, const bf16_t* __restrict__ Kg,
    const bf16_t* __restrict__ Vg, bf16_t* __restrict__ O,
    int b, int h, int q0, int ktiles, int tid,
    bf16_t (&Ks)[64][136], bf16_t (&Vs)[64][72], bf16_t (&Ps)[4][16][72]) {
    const int lane = tid & 63, wave = tid >> 6;
    const int n16 = lane & 15, quad = lane >> 4;
    const int qbase = q0 + wave * 16;

    const bf16_t* Qrow = Qg + (size_t)(qbase + n16) * 128;
    bf16x8 qf[4];
#pragma unroll
    for (int c = 0; c < 4; ++c)
        qf[c] = *(const bf16x8*)(Qrow + c * 32 + quad * 8);

    f32x4 oacc[4] = {};
    float mrow[4] = {-3e30f, -3e30f, -3e30f, -3e30f};
    float lrow[4] = {};
    const float scale = 0.051776695296636886f;  // 1/(sqrt(128)+sqrt(64))

    for (int t = 0; t < ktiles; ++t) {
        const int k0 = t << 6;
        __syncthreads();
#pragma unroll
        for (int c = 0; c < 4; ++c) {
            const int idx = tid + c * 256;
            const int r = idx >> 4, col = (idx & 15) << 3;
            *(bf16x8*)&Ks[r][col] = *(const bf16x8*)&Kg[(size_t)(k0 + r) * 128 + col];
        }
#pragma unroll
        for (int c = 0; c < 2; ++c) {
            const int idx = tid + c * 256;
            const int r = idx >> 3, col = (idx & 7) << 3;
            *(bf16x8*)&Vs[r][col] = *(const bf16x8*)&Vg[(size_t)r * S_ + k0 + col];
        }
        __syncthreads();

        f32x4 sacc[4] = {};
#pragma unroll
        for (int c = 0; c < 4; ++c) {
            const bf16x8 a = qf[c];
#pragma unroll
            for (int g = 0; g < 4; ++g) {
                bf16x8 kb = *(bf16x8*)&Ks[g * 16 + n16][c * 32 + quad * 8];
                sacc[g] = mfma16(a, kb, sacc[g]);
            }
        }

        const bool boundary = (k0 + 63 > qbase);
        float p[4][4];
#pragma unroll
        for (int g = 0; g < 4; ++g)
#pragma unroll
            for (int r = 0; r < 4; ++r) {
                float s = sacc[g][r] * scale;
                if (boundary && (k0 + g * 16 + n16 > qbase + quad * 4 + r))
                    s = -3e30f;
                p[g][r] = s;
            }

        float alpha[4];
#pragma unroll
        for (int r = 0; r < 4; ++r) {
            float mx = fmaxf(fmaxf(p[0][r], p[1][r]), fmaxf(p[2][r], p[3][r]));
            mx = fmaxf(mx, __shfl_xor(mx, 1));
            mx = fmaxf(mx, __shfl_xor(mx, 2));
            mx = fmaxf(mx, __shfl_xor(mx, 4));
            mx = fmaxf(mx, __shfl_xor(mx, 8));
            const float mn = fmaxf(mrow[r], mx);
            alpha[r] = __expf(mrow[r] - mn);
            mrow[r] = mn;
            float rs = 0.0f;
#pragma unroll
            for (int g = 0; g < 4; ++g) {
                const float e = __expf(p[g][r] - mn);
                p[g][r] = e;
                rs += e;
            }
            rs += __shfl_xor(rs, 1);
            rs += __shfl_xor(rs, 2);
            rs += __shfl_xor(rs, 4);
            rs += __shfl_xor(rs, 8);
            lrow[r] = lrow[r] * alpha[r] + rs;
        }
#pragma unroll
        for (int nt = 0; nt < 4; ++nt)
#pragma unroll
            for (int r = 0; r < 4; ++r)
                oacc[nt][r] *= alpha[r];

#pragma unroll
        for (int r = 0; r < 4; ++r)
#pragma unroll
            for (int g = 0; g < 4; ++g)
                Ps[wave][quad * 4 + r][g * 16 + n16] = (bf16_t)p[g][r];
        const bf16x8 pf0 = *(bf16x8*)&Ps[wave][n16][quad * 8];
        const bf16x8 pf1 = *(bf16x8*)&Ps[wave][n16][32 + quad * 8];
#pragma unroll
        for (int nt = 0; nt < 4; ++nt) {
            bf16x8 vb0 = *(bf16x8*)&Vs[nt * 16 + n16][quad * 8];
            bf16x8 vb1 = *(bf16x8*)&Vs[nt * 16 + n16][32 + quad * 8];
            oacc[nt] = mfma16(pf0, vb0, oacc[nt]);
            oacc[nt] = mfma16(pf1, vb1, oacc[nt]);
        }
    }

    float il[4];
#pragma unroll
    for (int r = 0; r < 4; ++r) il[r] = 1.0f / lrow[r];
#pragma unroll
    for (int nt = 0; nt < 4; ++nt)
#pragma unroll
        for (int r = 0; r < 4; ++r)
            O[((size_t)b * S_ + qbase + quad * 4 + r) * (size_t)(H_ * 64)
              + h * 64 + nt * 16 + n16] = (bf16_t)(oacc[nt][r] * il[r]);
}

__global__ __launch_bounds__(256, 4) void flash_fold(const bf16_t* __restrict__ Q,
                                                     const bf16_t* __restrict__ K,
                                                     const bf16_t* __restrict__ Vt,
                                                     bf16_t* __restrict__ O) {
    __shared__ bf16_t Ks[64][136];
    __shared__ bf16_t Vs[64][72];
    __shared__ bf16_t Ps[4][16][72];
    const int bh = blockIdx.y, b = bh >> 4, h = bh & 15;
    const bf16_t* Qg = Q + (size_t)bh * S_ * 128;
    const bf16_t* Kg = K + (size_t)bh * S_ * 128;
    const bf16_t* Vg = Vt + (size_t)bh * 64 * S_;
    const int j = blockIdx.x;  // 0..15; fold pairs (j, 31-j): uniform 33 tiles
    flash_pass(Qg, Kg, Vg, O, b, h, j << 6, j + 1, threadIdx.x, Ks, Vs, Ps);
    flash_pass(Qg, Kg, Vg, O, b, h, (31 - j) << 6, 32 - j, threadIdx.x, Ks, Vs, Ps);
}

// ---------------------------------------------------------------------------
extern "C" void kernel_launch(void* const* d_in, const int* in_sizes, int n_in,
                              void* d_out, int out_size, void* d_ws, size_t ws_size,
                              hipStream_t stream) {
    const float* X     = (const float*)d_in[0];
    const float* W_dkv = (const float*)d_in[2];
    const float* b_dkv = (const float*)d_in[3];
    const float* W_dq  = (const float*)d_in[4];
    const float* b_dq  = (const float*)d_in[5];
    const float* W_uk  = (const float*)d_in[6];
    const float* b_uk  = (const float*)d_in[7];
    const float* W_uv  = (const float*)d_in[8];
    const float* b_uv  = (const float*)d_in[9];
    const float* W_uq  = (const float*)d_in[10];
    const float* b_uq  = (const float*)d_in[11];
    const float* W_qr  = (const float*)d_in[12];
    const float* b_qr  = (const float*)d_in[13];
    const float* W_kr  = (const float*)d_in[14];
    const float* b_kr  = (const float*)d_in[15];
    const float* W_fc  = (const float*)d_in[16];
    const float* b_fc  = (const float*)d_in[17];
    float* out = (float*)d_out;

    char* w = (char*)d_ws;
    bf16_t* Xb     = (bf16_t*)(w);                // 8192x2048        33,554,432
    bf16_t* Wtdown = (bf16_t*)(w + 33554432);     // 1152x2048 bf16    4,718,592
    bf16_t* Wtup1  = (bf16_t*)(w + 38273024);     // 2048x512          2,097,152
    bf16_t* Wtup2  = (bf16_t*)(w + 40370176);     // 2048x512          2,097,152
    bf16_t* Wtfc   = (bf16_t*)(w + 42467328);     // 2048x1024         4,194,304
    bf16_t* ckv    = (bf16_t*)(w + 46661632);     // 8192x512          8,388,608
    bf16_t* cq     = (bf16_t*)(w + 55050240);     // 8192x512          8,388,608
    bf16_t* attnb  = (bf16_t*)(w + 46661632);     // 8192x1024, reuses ckv+cq
    bf16_t* Qb     = (bf16_t*)(w + 63438848);     // (64,2048,128)    33,554,432
    bf16_t* Kb     = (bf16_t*)(w + 96993280);     // (64,2048,128)    33,554,432
    bf16_t* Vt     = (bf16_t*)(w + 130547712);    // (64,64,2048)     16,777,216

    const dim3 blk(256);
    cast_bf16<<<16384, blk, 0, stream>>>(X, Xb, 16777216);
    // concatenated transposed weights
    transpose_cast<<<dim3(16, 64), blk, 0, stream>>>(W_dkv, Wtdown, 2048, 512);
    transpose_cast<<<dim3(16, 64), blk, 0, stream>>>(W_dq, Wtdown + (size_t)512 * 2048, 2048, 512);
    transpose_cast<<<dim3(2, 64), blk, 0, stream>>>(W_kr, Wtdown + (size_t)1024 * 2048, 2048, 64);
    transpose_cast<<<dim3(32, 16), blk, 0, stream>>>(W_uk, Wtup1, 512, 1024);
    transpose_cast<<<dim3(32, 16), blk, 0, stream>>>(W_uv, Wtup1 + (size_t)1024 * 512, 512, 1024);
    transpose_cast<<<dim3(32, 16), blk, 0, stream>>>(W_uq, Wtup2, 512, 1024);
    transpose_cast<<<dim3(32, 16), blk, 0, stream>>>(W_qr, Wtup2 + (size_t)1024 * 512, 512, 1024);
    transpose_cast<<<dim3(64, 32), blk, 0, stream>>>(W_fc, Wtfc, 1024, 2048);
    // down-proj + k_r fused (N=1152: 512 ckv | 512 cq | 64 k_r | 64 dead)
    mgemm<6><<<dim3(9, 64), blk, 0, stream>>>(Xb, Wtdown, b_dkv, b_dq, b_kr,
                                              ckv, cq, Kb, MTOK, 1152, 2048);
    // up-projs fused
    mgemm<7><<<dim3(16, 64), blk, 0, stream>>>(ckv, Wtup1, b_uk, b_uv, nullptr,
                                               Kb, Vt, nullptr, MTOK, 2048, 512);
    mgemm<8><<<dim3(16, 64), blk, 0, stream>>>(cq, Wtup2, b_uq, b_qr, nullptr,
                                               Qb, nullptr, nullptr, MTOK, 2048, 512);
    // balanced causal flash attention
    flash_fold<<<dim3(16, 64), blk, 0, stream>>>(Qb, Kb, Vt, attnb);
    // out-proj
    mgemm<5><<<dim3(16, 64), blk, 0, stream>>>(attnb, Wtfc, b_fc, nullptr, nullptr,
                                               out, nullptr, nullptr, MTOK, 2048, 1024);
}